// Round 15
// baseline (131.401 us; speedup 1.0000x reference)
//
#include <hip/hip_runtime.h>
#include <stdint.h>

typedef __attribute__((ext_vector_type(4))) int i32x4;
typedef __attribute__((ext_vector_type(16))) int i32x16;
typedef __attribute__((ext_vector_type(8))) short short8;
typedef __attribute__((ext_vector_type(16))) float f32x16;

#define LOG2E 1.4426950408889634f
// Power-of-2 quantization scales (A raw, B pre-scaled by log2e):
//   hi = rint(x*16), lo = rint((x - hi/16)*4096)
//   c = (float)((hh << 8) + m) * 2^-16
#define S1 16.0f
#define S1_INV 0.0625f
#define S2 4096.0f
#define K2 (1.0f / 65536.0f)

__device__ inline float fast_exp2(float x) {
#if __has_builtin(__builtin_amdgcn_exp2f)
  return __builtin_amdgcn_exp2f(x);
#else
  float r;
  asm("v_exp_f32 %0, %1" : "=v"(r) : "v"(x));
  return r;
#endif
}

__device__ inline void gload16(const void* g, void* l) {
  __builtin_amdgcn_global_load_lds(
      (const __attribute__((address_space(1))) void*)g,
      (__attribute__((address_space(3))) void*)l, 16, 0, 0);
}
__device__ inline void gload4(const void* g, void* l) {
  __builtin_amdgcn_global_load_lds(
      (const __attribute__((address_space(1))) void*)g,
      (__attribute__((address_space(3))) void*)l, 4, 0, 0);
}

// Quantize 4 floats (optionally pre-scaled) to int8 hi/lo pairs packed into
// one int each (byte j = element j).
__device__ inline void q4(float4 v, float pre, int& hw, int& lw) {
  float xs[4] = {v.x, v.y, v.z, v.w};
  int h = 0, l = 0;
#pragma unroll
  for (int j = 0; j < 4; ++j) {
    float x = xs[j] * pre;
    float hf = rintf(fminf(fmaxf(x * S1, -127.f), 127.f));
    float rf = x - hf * S1_INV;
    float lf = rintf(fminf(fmaxf(rf * S2, -127.f), 127.f));
    h |= ((int)hf & 255) << (8 * j);
    l |= ((int)lf & 255) << (8 * j);
  }
  hw = h;
  lw = l;
}

// ---------------------------------------------------------------------------
// FUSED conversion + s: Xtr f32 -> int8 hi/lo fragment-tiled planes
// ([plane(2)][kf(4)][lk(2)][row(32)][16B] per 32-row 8 KB tile) AND
// s[m] = exp(-||y_m||^2/2) * w[m] via 8-lane in-wave reduction.
// ---------------------------------------------------------------------------
__global__ __launch_bounds__(256) void gk_conv_s(const float* __restrict__ Xtr,
                                                 const float* __restrict__ wts,
                                                 char* __restrict__ planes,
                                                 float* __restrict__ s, int M) {
  int g = blockIdx.x * 256 + threadIdx.x;  // granule id: row*8 + gr
  int row = g >> 3;
  int gr = g & 7;  // 16 k-elems: kf = gr>>1, lk = gr&1
  if (row >= M) return;
  const float* p = Xtr + (size_t)row * 128 + gr * 16;
  int hw[4], lw[4];
  float ss = 0.f;
#pragma unroll
  for (int i = 0; i < 4; ++i) {
    float4 v = *(const float4*)(p + i * 4);
    ss += v.x * v.x + v.y * v.y + v.z * v.z + v.w * v.w;
    q4(v, 1.0f, hw[i], lw[i]);
  }
  ss += __shfl_xor(ss, 1, 64);
  ss += __shfl_xor(ss, 2, 64);
  ss += __shfl_xor(ss, 4, 64);
  if (gr == 0) s[row] = expf(-0.5f * ss) * wts[row];

  int T = row >> 5, r = row & 31;
  size_t base = (size_t)T * 8192 + (gr >> 1) * 1024 + (gr & 1) * 512 + r * 16;
  *(i32x4*)(planes + base) = (i32x4){hw[0], hw[1], hw[2], hw[3]};
  *(i32x4*)(planes + base + 4096) = (i32x4){lw[0], lw[1], lw[2], lw[3]};
}

// ---------------------------------------------------------------------------
// Main kernel (i8x2, 1-DEEP acc in VGPRs, loop-invariant ZERO as MFMA C,
// counted-vmcnt 4-buffer). Block = 256 thr = 4 waves; wave = 32x32 tile;
// block covers 128 cols; grid 64x16 = 1024 = 4 blocks/CU.
// WHY 1-deep: R10/R14 counters (MfmaUtil+VALUBusy pinned at ~99% across 3
// structures, runtime additive in the two) show MFMA and VALU share the
// SIMD execution hardware -- no overlap is possible, so the 2-deep pipeline
// bought nothing and its 64 acc regs forced the accumulators into AGPRs
// (VGPR_Count=64 signature), adding ~64 v_accvgpr_read/write per iter.
// The only lever is LESS WORK:
//  (1) 1 acc set (32 regs) -> live ~100 <= 128 -> accs stay in VGPRs,
//      EPI reads them directly (no shuttle);
//  (2) chain-head MFMAs take a LOOP-INVARIANT zero vector as C (C != D is
//      legal SSA with builtins) -> zero-init movs leave the loop.
// Schedule: [sched_barrier; STAGE(t+2); MFMA(t); EPI(t); vmcnt(3); barrier].
// STAGE = 3 VMEM/thread -> vmcnt(3) == previous stage landed. WAR-safe:
// stage(t+2) writes buf (t-2)&3, whose readers finished 2 barriers ago.
// Tail: clamped dummy stage keeps per-wave VMEM counts uniform.
// ---------------------------------------------------------------------------
__global__ __launch_bounds__(256, 4) void gk_main_i8(
    const float* __restrict__ Xnew, const char* __restrict__ planes,
    const float* __restrict__ s, float* __restrict__ out, int N, int M,
    int mchunk) {
  extern __shared__ char dlds[];  // [4 x 8192 A-bufs][4 x 256 s-bufs]

  const int t = threadIdx.x;
  const int l = t & 63;
  const int w = t >> 6;   // wave 0..3
  const int cl = l & 31;  // B-col within frag / A-row within frag
  const int lk = l >> 5;  // k-chunk half

  const int n0 = blockIdx.x * 128;
  const int M0 = blockIdx.y * mchunk;
  const int iters = mchunk >> 5;  // 64
  const int T0 = M0 >> 5;

#define STAGE(tt)                                                       \
  {                                                                     \
    int st_ = ((tt) < iters) ? (tt) : (iters - 1); /* clamped dummy */  \
    const char* src_ = planes + (size_t)(T0 + st_) * 8192 + t * 16;     \
    char* dst_ = dlds + ((tt)&3) * 8192 + t * 16;                       \
    gload16(src_, dst_);                                                \
    gload16(src_ + 4096, dst_ + 4096);                                  \
    gload4(s + M0 + st_ * 32 + l, dlds + 32768 + ((tt)&3) * 256);       \
  }

  // 12 builtin MFMAs; chain heads consume the loop-invariant zero vector zc
  // as C (no per-iter acc zero-init).
#define MFMAS_Z(acc_hh, acc_m, tile)                                    \
  {                                                                     \
    const char* buf_ = dlds + ((tile)&3) * 8192;                        \
    {                                                                   \
      const char* kb_ = buf_ + lk * 512 + cl * 16;                      \
      i32x4 ah_ = *(const i32x4*)(kb_);                                 \
      i32x4 al_ = *(const i32x4*)(kb_ + 4096);                          \
      acc_hh = __builtin_amdgcn_mfma_i32_32x32x32_i8(ah_, bh[0], zc, 0, 0, 0);      \
      acc_m = __builtin_amdgcn_mfma_i32_32x32x32_i8(ah_, bl[0], zc, 0, 0, 0);       \
      acc_m = __builtin_amdgcn_mfma_i32_32x32x32_i8(al_, bh[0], acc_m, 0, 0, 0);    \
    }                                                                   \
    _Pragma("unroll") for (int kf = 1; kf < 4; ++kf) {                  \
      const char* kb_ = buf_ + kf * 1024 + lk * 512 + cl * 16;          \
      i32x4 ah_ = *(const i32x4*)(kb_);                                 \
      i32x4 al_ = *(const i32x4*)(kb_ + 4096);                          \
      acc_hh = __builtin_amdgcn_mfma_i32_32x32x32_i8(ah_, bh[kf], acc_hh, 0, 0, 0); \
      acc_m = __builtin_amdgcn_mfma_i32_32x32x32_i8(ah_, bl[kf], acc_m, 0, 0, 0);   \
      acc_m = __builtin_amdgcn_mfma_i32_32x32x32_i8(al_, bh[kf], acc_m, 0, 0, 0);   \
    }                                                                   \
  }

  // epilogue: c = ((hh<<8)+m)*2^-16 = log2e*<x,y>; exp2; * s[m].
  // C/D layout (verified): col = lane&31, row = (reg&3)+8*(reg>>2)+4*lk
#define EPI(acc_hh, acc_m, tile)                                        \
  {                                                                     \
    const float4* sl4_ =                                                \
        (const float4*)(dlds + 32768 + ((tile)&3) * 256);               \
    _Pragma("unroll") for (int q = 0; q < 4; ++q) {                     \
      float4 sv_ = sl4_[q * 2 + lk];                                    \
      _Pragma("unroll") for (int j = 0; j < 4; ++j) {                   \
        int r_ = q * 4 + j;                                             \
        float c_ = (float)((acc_hh[r_] << 8) + acc_m[r_]) * K2;         \
        out0 += fast_exp2(c_) * (&sv_.x)[j];                            \
      }                                                                 \
    }                                                                   \
  }

#define REGION_END                                                      \
  asm volatile("s_waitcnt vmcnt(3)" ::: "memory");                      \
  __builtin_amdgcn_s_barrier();

  // ---- issue stage(0), stage(1) first so DMA overlaps B-init --------------
  STAGE(0);
  STAGE(1);

  // ---- per-wave B-panel (32 cols x K=128, i8 hi/lo, log2e folded) and
  // ---- in-register pref for the wave's cols (reuses the same loads) -------
  i32x4 bh[4], bl[4];
  float pref;
  {
    float ss = 0.f;
    const float* pc = Xnew + (size_t)(n0 + w * 32 + cl) * 128;
#pragma unroll
    for (int kf = 0; kf < 4; ++kf) {
      const float* p = pc + kf * 32 + lk * 16;
      int hw[4], lw[4];
#pragma unroll
      for (int i = 0; i < 4; ++i) {
        float4 v = *(const float4*)(p + i * 4);
        ss += v.x * v.x + v.y * v.y + v.z * v.z + v.w * v.w;
        q4(v, LOG2E, hw[i], lw[i]);
      }
      bh[kf] = (i32x4){hw[0], hw[1], hw[2], hw[3]};
      bl[kf] = (i32x4){lw[0], lw[1], lw[2], lw[3]};
    }
    ss += __shfl_xor(ss, 32, 64);  // combine the two k-halves of the col
    pref = expf(-0.5f * ss);
  }

  float out0 = 0.f;
  // loop-invariant zero C-operand (16 regs, zeroed once)
  const i32x16 zc = {0, 0, 0, 0, 0, 0, 0, 0, 0, 0, 0, 0, 0, 0, 0, 0};
  i32x16 hh, m;

  asm volatile("s_waitcnt vmcnt(3)" ::: "memory");  // stage(0) landed
  __builtin_amdgcn_s_barrier();

  // ---- main loop: 1-deep, EPI(t) right after MFMA(t) ----------------------
#pragma unroll 1
  for (int it = 0; it < iters; ++it) {
    __builtin_amdgcn_sched_barrier(0);
    STAGE(it + 2);
    MFMAS_Z(hh, m, it);
    EPI(hh, m, it);
    REGION_END;
  }

  // ---- reduce row-halves (lane>>5) + atomic -------------------------------
  out0 += __shfl_xor(out0, 32, 64);
  if (l < 32) {
    int n = n0 + w * 32 + l;
    atomicAdd(out + n, pref * out0);
  }
#undef STAGE
#undef MFMAS_Z
#undef EPI
#undef REGION_END
}

// ---------------------------------------------------------------------------
// FALLBACK (ws too small): bf16x3 R1-structure (known-good ~185 us) + prep.
// ---------------------------------------------------------------------------
__global__ __launch_bounds__(256) void gk_prep(
    const float* __restrict__ Xnew, const float* __restrict__ Xtr,
    const float* __restrict__ w, float* __restrict__ s,
    float* __restrict__ pref, int M, int N) {
  int row = blockIdx.x * 4 + (threadIdx.x >> 6);
  int lane = threadIdx.x & 63;
  if (row >= M + N) return;
  const float* src =
      (row < M) ? (Xtr + (size_t)row * 128) : (Xnew + (size_t)(row - M) * 128);
  float2 v = *(const float2*)(src + lane * 2);
  float ss = v.x * v.x + v.y * v.y;
#pragma unroll
  for (int o = 32; o >= 1; o >>= 1) ss += __shfl_xor(ss, o, 64);
  if (lane == 0) {
    float e = expf(-0.5f * ss);
    if (row < M)
      s[row] = e * w[row];
    else
      pref[row - M] = e;
  }
}

__device__ inline unsigned swz_fb(unsigned off) {
  return off ^ (((off >> 8) & 7u) << 4);
}
__device__ inline void split8(float x0, float x1, float x2, float x3,
                              float x4, float x5, float x6, float x7,
                              float scale, short8& hi, short8& lo) {
  float xs[8] = {x0, x1, x2, x3, x4, x5, x6, x7};
#pragma unroll
  for (int i = 0; i < 8; ++i) {
    float v = xs[i] * scale;
    unsigned u = __float_as_uint(v);
    float hf = __uint_as_float(u & 0xffff0000u);
    float rr = v - hf;
    hi[i] = (short)(u >> 16);
    lo[i] = (short)(__float_as_uint(rr) >> 16);
  }
}

__global__ __launch_bounds__(256, 2) void gk_main_fb(
    const float* __restrict__ Xnew, const float* __restrict__ Xtr,
    const float* __restrict__ s, const float* __restrict__ pref,
    float* __restrict__ out, int N, int M, int mchunk) {
  __shared__ __attribute__((aligned(16))) char lds[33024];
  const int t = threadIdx.x;
  const int l = t & 63;
  const int w = t >> 6;
  const int lrow = l & 31;
  const int lk = l >> 5;
  const int n0 = blockIdx.x * 256;
  const int M0 = blockIdx.y * mchunk;
  const int iters = mchunk >> 6;

  short8 bh[2][8], bl[2][8];
  {
    const int colbase = n0 + w * 64;
#pragma unroll
    for (int nf = 0; nf < 2; ++nf) {
      int col = colbase + nf * 32 + lrow;
      const float* p = Xnew + (size_t)col * 128 + lk * 8;
#pragma unroll
      for (int kf = 0; kf < 8; ++kf) {
        float4 f0 = *(const float4*)(p + kf * 16);
        float4 f1 = *(const float4*)(p + kf * 16 + 4);
        split8(f0.x, f0.y, f0.z, f0.w, f1.x, f1.y, f1.z, f1.w, LOG2E,
               bh[nf][kf], bl[nf][kf]);
      }
    }
  }

  float out0 = 0.f, out1 = 0.f;
  float4 ga[4][2];
  float sreg = 0.f;
  {
    const float* abase = Xtr + (size_t)M0 * 128;
#pragma unroll
    for (int j = 0; j < 4; ++j) {
      int c = t + j * 256;
      int row = c >> 4, oct = c & 15;
      const float* p = abase + (size_t)row * 128 + oct * 8;
      ga[j][0] = *(const float4*)p;
      ga[j][1] = *(const float4*)(p + 4);
    }
    if (t < 64) sreg = s[M0 + t];
  }

#pragma unroll 1
  for (int it = 0; it < iters; ++it) {
    __syncthreads();
#pragma unroll
    for (int j = 0; j < 4; ++j) {
      int c = t + j * 256;
      int row = c >> 4, oct = c & 15;
      unsigned off = swz_fb((unsigned)(row * 256 + oct * 16));
      short8 hi, lo;
      split8(ga[j][0].x, ga[j][0].y, ga[j][0].z, ga[j][0].w, ga[j][1].x,
             ga[j][1].y, ga[j][1].z, ga[j][1].w, 1.0f, hi, lo);
      *(short8*)(lds + off) = hi;
      *(short8*)(lds + 16384 + off) = lo;
    }
    if (t < 64) *(float*)(lds + 32768 + t * 4) = sreg;
    __syncthreads();
    if (it + 1 < iters) {
      const float* abase = Xtr + (size_t)(M0 + (it + 1) * 64) * 128;
#pragma unroll
      for (int j = 0; j < 4; ++j) {
        int c = t + j * 256;
        int row = c >> 4, oct = c & 15;
        const float* p = abase + (size_t)row * 128 + oct * 8;
        ga[j][0] = *(const float4*)p;
        ga[j][1] = *(const float4*)(p + 4);
      }
      if (t < 64) sreg = s[M0 + (it + 1) * 64 + t];
    }
#pragma unroll
    for (int mf = 0; mf < 2; ++mf) {
      f32x16 acc0 = {0, 0, 0, 0, 0, 0, 0, 0, 0, 0, 0, 0, 0, 0, 0, 0};
      f32x16 acc1 = {0, 0, 0, 0, 0, 0, 0, 0, 0, 0, 0, 0, 0, 0, 0, 0};
#pragma unroll
      for (int kf = 0; kf < 8; ++kf) {
        unsigned off =
            swz_fb((unsigned)((mf * 32 + lrow) * 256 + kf * 32 + lk * 16));
        short8 ah = *(const short8*)(lds + off);
        short8 al = *(const short8*)(lds + 16384 + off);
        acc0 = __builtin_amdgcn_mfma_f32_32x32x16_bf16(ah, bh[0][kf], acc0, 0, 0, 0);
        acc1 = __builtin_amdgcn_mfma_f32_32x32x16_bf16(ah, bh[1][kf], acc1, 0, 0, 0);
        acc0 = __builtin_amdgcn_mfma_f32_32x32x16_bf16(ah, bl[0][kf], acc0, 0, 0, 0);
        acc1 = __builtin_amdgcn_mfma_f32_32x32x16_bf16(ah, bl[1][kf], acc1, 0, 0, 0);
        acc0 = __builtin_amdgcn_mfma_f32_32x32x16_bf16(al, bh[0][kf], acc0, 0, 0, 0);
        acc1 = __builtin_amdgcn_mfma_f32_32x32x16_bf16(al, bh[1][kf], acc1, 0, 0, 0);
      }
      const float* sl = (const float*)(lds + 32768 + mf * 128);
#pragma unroll
      for (int r = 0; r < 16; ++r) {
        int row = (r & 3) + 8 * (r >> 2) + 4 * lk;
        float sv = sl[row];
        out0 += fast_exp2(acc0[r]) * sv;
        out1 += fast_exp2(acc1[r]) * sv;
      }
    }
  }
  out0 += __shfl_xor(out0, 32, 64);
  out1 += __shfl_xor(out1, 32, 64);
  if (l < 32) {
    int n = n0 + w * 64 + l;
    atomicAdd(out + n, pref[n] * out0);
    n += 32;
    atomicAdd(out + n, pref[n] * out1);
  }
}

extern "C" void kernel_launch(void* const* d_in, const int* in_sizes, int n_in,
                              void* d_out, int out_size, void* d_ws,
                              size_t ws_size, hipStream_t stream) {
  const float* Xnew = (const float*)d_in[0];
  const float* Xtr = (const float*)d_in[1];
  const float* wts = (const float*)d_in[2];
  float* out = (float*)d_out;

  const int N = in_sizes[0] / 128;  // 8192
  const int M = in_sizes[1] / 128;  // 32768

  char* ws = (char*)d_ws;
  float* s_ws = (float*)ws;                 // [M]
  char* planes_ws = ws + (size_t)M * 4;     // [M*256 B], 16B-aligned
  const size_t need = (size_t)M * 4 + (size_t)M * 256;

  hipMemsetAsync(d_out, 0, (size_t)N * sizeof(float), stream);

  if (ws_size >= need) {
    gk_conv_s<<<dim3(M * 8 / 256), 256, 0, stream>>>(Xtr, wts, planes_ws,
                                                     s_ws, M);
    const int SPLIT = 16;
    dim3 grid(N / 128, SPLIT);  // 64 x 16 = 1024 blocks = 4/CU
    gk_main_i8<<<grid, 256, 33792, stream>>>(Xnew, planes_ws, s_ws, out, N, M,
                                             M / SPLIT);
  } else {
    float* pref_ws = s_ws + M;
    int rows = M + N;
    gk_prep<<<dim3((rows + 3) / 4), 256, 0, stream>>>(Xnew, Xtr, wts, s_ws,
                                                      pref_ws, M, N);
    const int SPLIT = 16;
    dim3 grid(N / 256, SPLIT);
    gk_main_fb<<<grid, 256, 0, stream>>>(Xnew, Xtr, s_ws, pref_ws, out, N, M,
                                         M / SPLIT);
  }
}

// Round 16
// 131.112 us; speedup vs baseline: 1.0022x; 1.0022x over previous
//
#include <hip/hip_runtime.h>
#include <stdint.h>

typedef __attribute__((ext_vector_type(4))) int i32x4;
typedef __attribute__((ext_vector_type(16))) int i32x16;
typedef __attribute__((ext_vector_type(8))) short short8;
typedef __attribute__((ext_vector_type(16))) float f32x16;

#define LOG2E 1.4426950408889634f
// Power-of-2 quantization scales (A raw, B pre-scaled by log2e):
//   hi = rint(x*16), lo = rint((x - hi/16)*4096)
//   c = (float)((hh << 8) + m) * 2^-16
#define S1 16.0f
#define S1_INV 0.0625f
#define S2 4096.0f
#define K2 (1.0f / 65536.0f)

__device__ inline float fast_exp2(float x) {
#if __has_builtin(__builtin_amdgcn_exp2f)
  return __builtin_amdgcn_exp2f(x);
#else
  float r;
  asm("v_exp_f32 %0, %1" : "=v"(r) : "v"(x));
  return r;
#endif
}

__device__ inline void gload16(const void* g, void* l) {
  __builtin_amdgcn_global_load_lds(
      (const __attribute__((address_space(1))) void*)g,
      (__attribute__((address_space(3))) void*)l, 16, 0, 0);
}
__device__ inline void gload4(const void* g, void* l) {
  __builtin_amdgcn_global_load_lds(
      (const __attribute__((address_space(1))) void*)g,
      (__attribute__((address_space(3))) void*)l, 4, 0, 0);
}

// Quantize 4 floats (optionally pre-scaled) to int8 hi/lo pairs packed into
// one int each (byte j = element j).
__device__ inline void q4(float4 v, float pre, int& hw, int& lw) {
  float xs[4] = {v.x, v.y, v.z, v.w};
  int h = 0, l = 0;
#pragma unroll
  for (int j = 0; j < 4; ++j) {
    float x = xs[j] * pre;
    float hf = rintf(fminf(fmaxf(x * S1, -127.f), 127.f));
    float rf = x - hf * S1_INV;
    float lf = rintf(fminf(fmaxf(rf * S2, -127.f), 127.f));
    h |= ((int)hf & 255) << (8 * j);
    l |= ((int)lf & 255) << (8 * j);
  }
  hw = h;
  lw = l;
}

// ---------------------------------------------------------------------------
// FUSED conversion + s: Xtr f32 -> int8 hi/lo fragment-tiled planes
// ([plane(2)][kf(4)][lk(2)][row(32)][16B] per 32-row 8 KB tile) AND
// s[m] = exp(-||y_m||^2/2) * w[m] via 8-lane in-wave reduction.
// ---------------------------------------------------------------------------
__global__ __launch_bounds__(256) void gk_conv_s(const float* __restrict__ Xtr,
                                                 const float* __restrict__ wts,
                                                 char* __restrict__ planes,
                                                 float* __restrict__ s, int M) {
  int g = blockIdx.x * 256 + threadIdx.x;  // granule id: row*8 + gr
  int row = g >> 3;
  int gr = g & 7;  // 16 k-elems: kf = gr>>1, lk = gr&1
  if (row >= M) return;
  const float* p = Xtr + (size_t)row * 128 + gr * 16;
  int hw[4], lw[4];
  float ss = 0.f;
#pragma unroll
  for (int i = 0; i < 4; ++i) {
    float4 v = *(const float4*)(p + i * 4);
    ss += v.x * v.x + v.y * v.y + v.z * v.z + v.w * v.w;
    q4(v, 1.0f, hw[i], lw[i]);
  }
  ss += __shfl_xor(ss, 1, 64);
  ss += __shfl_xor(ss, 2, 64);
  ss += __shfl_xor(ss, 4, 64);
  if (gr == 0) s[row] = expf(-0.5f * ss) * wts[row];

  int T = row >> 5, r = row & 31;
  size_t base = (size_t)T * 8192 + (gr >> 1) * 1024 + (gr & 1) * 512 + r * 16;
  *(i32x4*)(planes + base) = (i32x4){hw[0], hw[1], hw[2], hw[3]};
  *(i32x4*)(planes + base + 4096) = (i32x4){lw[0], lw[1], lw[2], lw[3]};
}

// ---------------------------------------------------------------------------
// Main kernel (i8x2, 64x32 wave tile, 3 waves/SIMD, counted-vmcnt 3-buffer).
// Block = 256 thr = 4 waves; wave tile = 64 A-rows (2 m-frags) x 32 B-cols,
// B-panel shared by both frags; block covers 128 cols.
// WHY: R10-R15 counters prove MFMA and VALU serialize on the SIMD
// (MfmaUtil+VALUBusy pinned ~100%, runtime additive), so scheduling is dead;
// per-output MFMA and EPI are fixed; the lever is per-TILE overhead
// (staging addr math, loop/sync, accvgpr shuttle). The 64-row wave tile
// halves that overhead per output, and 3 waves/SIMD (__launch_bounds 256,3
// -> 170 regs) gives the allocator room to keep the 64 acc regs in VGPRs.
// Geometry: grid 64x12 = 768 = 3 blocks/CU; LDS = 3 x 16 KB pair-tiles +
// 3 x 256 B s-chunks = 49920 B (3 blocks/CU fits 160 KB).
// Schedule: [sched_barrier; STAGE(p+2); 24 MFMA; 32-elem EPI; vmcnt(5);
// s_barrier]. STAGE = 5 VMEM/thread (4 gload16 + gload4) -> vmcnt(5) ==
// previous stage landed. WAR-safe: stage(p+2) writes slot (p+2)%3 =
// (p-1)%3, whose readers finished before the barrier ending iter p-1.
// Tail: clamped dummy stage keeps per-thread VMEM counts uniform (R14).
// ---------------------------------------------------------------------------
__global__ __launch_bounds__(256, 3) void gk_main_i8(
    const float* __restrict__ Xnew, const char* __restrict__ planes,
    const float* __restrict__ s, float* __restrict__ out, int N, int M,
    int mchunk) {
  extern __shared__ char dlds[];  // [3 x 16384 pair-bufs][3 x 256 s-bufs]

  const int t = threadIdx.x;
  const int l = t & 63;
  const int w = t >> 6;   // wave 0..3
  const int cl = l & 31;  // B-col within frag / A-row within frag
  const int lk = l >> 5;  // k-chunk half

  const int n0 = blockIdx.x * 128;
  const int M0 = blockIdx.y * mchunk;
  const int Mend = (M0 + mchunk < M) ? (M0 + mchunk) : M;
  const int P = (Mend - M0) >> 6;  // 64-row pairs (43 or 39)
  const int T0p = M0 >> 6;         // pair-tile base (16 KB units)

#define ZERO16 ((i32x16){0, 0, 0, 0, 0, 0, 0, 0, 0, 0, 0, 0, 0, 0, 0, 0})

#define STAGE(pp)                                                       \
  {                                                                     \
    int st_ = ((pp) < P) ? (pp) : (P - 1); /* clamped dummy */          \
    const char* src_ = planes + (size_t)(T0p + st_) * 16384 + t * 16;   \
    char* dst_ = dlds + ((pp) % 3) * 16384 + t * 16;                    \
    gload16(src_, dst_);                                                \
    gload16(src_ + 4096, dst_ + 4096);                                  \
    gload16(src_ + 8192, dst_ + 8192);                                  \
    gload16(src_ + 12288, dst_ + 12288);                                \
    gload4(s + M0 + st_ * 64 + l, dlds + 49152 + ((pp) % 3) * 256);     \
  }

  // 24 builtin MFMAs: 2 m-frags (tiles 2p, 2p+1) sharing bh/bl; chain heads
  // consume the loop-invariant zero vector zc (no per-iter acc init).
#define MFMAS_Z(hA, mA, hB, mB, pp)                                     \
  {                                                                     \
    const char* buf_ = dlds + ((pp) % 3) * 16384;                       \
    {                                                                   \
      const char* k0_ = buf_ + lk * 512 + cl * 16;                      \
      i32x4 a0h_ = *(const i32x4*)(k0_);                                \
      i32x4 a0l_ = *(const i32x4*)(k0_ + 4096);                         \
      i32x4 a1h_ = *(const i32x4*)(k0_ + 8192);                         \
      i32x4 a1l_ = *(const i32x4*)(k0_ + 12288);                        \
      hA = __builtin_amdgcn_mfma_i32_32x32x32_i8(a0h_, bh[0], zc, 0, 0, 0);      \
      mA = __builtin_amdgcn_mfma_i32_32x32x32_i8(a0h_, bl[0], zc, 0, 0, 0);      \
      mA = __builtin_amdgcn_mfma_i32_32x32x32_i8(a0l_, bh[0], mA, 0, 0, 0);      \
      hB = __builtin_amdgcn_mfma_i32_32x32x32_i8(a1h_, bh[0], zc, 0, 0, 0);      \
      mB = __builtin_amdgcn_mfma_i32_32x32x32_i8(a1h_, bl[0], zc, 0, 0, 0);      \
      mB = __builtin_amdgcn_mfma_i32_32x32x32_i8(a1l_, bh[0], mB, 0, 0, 0);      \
    }                                                                   \
    _Pragma("unroll") for (int kf = 1; kf < 4; ++kf) {                  \
      const char* k0_ = buf_ + kf * 1024 + lk * 512 + cl * 16;          \
      i32x4 a0h_ = *(const i32x4*)(k0_);                                \
      i32x4 a0l_ = *(const i32x4*)(k0_ + 4096);                         \
      i32x4 a1h_ = *(const i32x4*)(k0_ + 8192);                         \
      i32x4 a1l_ = *(const i32x4*)(k0_ + 12288);                        \
      hA = __builtin_amdgcn_mfma_i32_32x32x32_i8(a0h_, bh[kf], hA, 0, 0, 0);     \
      mA = __builtin_amdgcn_mfma_i32_32x32x32_i8(a0h_, bl[kf], mA, 0, 0, 0);     \
      mA = __builtin_amdgcn_mfma_i32_32x32x32_i8(a0l_, bh[kf], mA, 0, 0, 0);     \
      hB = __builtin_amdgcn_mfma_i32_32x32x32_i8(a1h_, bh[kf], hB, 0, 0, 0);     \
      mB = __builtin_amdgcn_mfma_i32_32x32x32_i8(a1h_, bl[kf], mB, 0, 0, 0);     \
      mB = __builtin_amdgcn_mfma_i32_32x32x32_i8(a1l_, bh[kf], mB, 0, 0, 0);     \
    }                                                                   \
  }

  // epilogue, both frags: c = ((hh<<8)+m)*2^-16 = log2e*<x,y>; exp2; *s[m].
  // C/D layout (verified): col = lane&31, row = (reg&3)+8*(reg>>2)+4*lk;
  // frag B rows are +32 (s float4 index +8).
#define EPI2(hA, mA, hB, mB, pp)                                        \
  {                                                                     \
    const float4* sl4_ =                                                \
        (const float4*)(dlds + 49152 + ((pp) % 3) * 256);               \
    _Pragma("unroll") for (int q = 0; q < 4; ++q) {                     \
      float4 sv0_ = sl4_[q * 2 + lk];                                   \
      float4 sv1_ = sl4_[8 + q * 2 + lk];                               \
      _Pragma("unroll") for (int j = 0; j < 4; ++j) {                   \
        int r_ = q * 4 + j;                                             \
        float cA_ = (float)((hA[r_] << 8) + mA[r_]) * K2;               \
        float cB_ = (float)((hB[r_] << 8) + mB[r_]) * K2;               \
        out0 += fast_exp2(cA_) * (&sv0_.x)[j];                          \
        out0 += fast_exp2(cB_) * (&sv1_.x)[j];                          \
      }                                                                 \
    }                                                                   \
  }

  // ---- issue stage(0), stage(1) first so DMA overlaps B-init --------------
  STAGE(0);
  STAGE(1);

  // ---- per-wave B-panel (32 cols x K=128, i8 hi/lo, log2e folded) and
  // ---- in-register pref for the wave's cols (reuses the same loads) -------
  i32x4 bh[4], bl[4];
  float pref;
  {
    float ss = 0.f;
    const float* pc = Xnew + (size_t)(n0 + w * 32 + cl) * 128;
#pragma unroll
    for (int kf = 0; kf < 4; ++kf) {
      const float* p = pc + kf * 32 + lk * 16;
      int hw[4], lw[4];
#pragma unroll
      for (int i = 0; i < 4; ++i) {
        float4 v = *(const float4*)(p + i * 4);
        ss += v.x * v.x + v.y * v.y + v.z * v.z + v.w * v.w;
        q4(v, LOG2E, hw[i], lw[i]);
      }
      bh[kf] = (i32x4){hw[0], hw[1], hw[2], hw[3]};
      bl[kf] = (i32x4){lw[0], lw[1], lw[2], lw[3]};
    }
    ss += __shfl_xor(ss, 32, 64);  // combine the two k-halves of the col
    pref = expf(-0.5f * ss);
  }

  float out0 = 0.f;
  const i32x16 zc = ZERO16;  // loop-invariant zero C-operand
  i32x16 hA, mA, hB, mB;

  asm volatile("s_waitcnt vmcnt(5)" ::: "memory");  // stage(0) landed
  __builtin_amdgcn_s_barrier();

  // ---- main loop ----------------------------------------------------------
#pragma unroll 1
  for (int p = 0; p < P; ++p) {
    __builtin_amdgcn_sched_barrier(0);
    STAGE(p + 2);
    MFMAS_Z(hA, mA, hB, mB, p);
    EPI2(hA, mA, hB, mB, p);
    asm volatile("s_waitcnt vmcnt(5)" ::: "memory");
    __builtin_amdgcn_s_barrier();
  }

  // ---- reduce row-halves (lane>>5) + atomic -------------------------------
  out0 += __shfl_xor(out0, 32, 64);
  if (l < 32) {
    int n = n0 + w * 32 + l;
    atomicAdd(out + n, pref * out0);
  }
#undef STAGE
#undef MFMAS_Z
#undef EPI2
#undef ZERO16
}

// ---------------------------------------------------------------------------
// FALLBACK (ws too small): bf16x3 R1-structure (known-good ~185 us) + prep.
// ---------------------------------------------------------------------------
__global__ __launch_bounds__(256) void gk_prep(
    const float* __restrict__ Xnew, const float* __restrict__ Xtr,
    const float* __restrict__ w, float* __restrict__ s,
    float* __restrict__ pref, int M, int N) {
  int row = blockIdx.x * 4 + (threadIdx.x >> 6);
  int lane = threadIdx.x & 63;
  if (row >= M + N) return;
  const float* src =
      (row < M) ? (Xtr + (size_t)row * 128) : (Xnew + (size_t)(row - M) * 128);
  float2 v = *(const float2*)(src + lane * 2);
  float ss = v.x * v.x + v.y * v.y;
#pragma unroll
  for (int o = 32; o >= 1; o >>= 1) ss += __shfl_xor(ss, o, 64);
  if (lane == 0) {
    float e = expf(-0.5f * ss);
    if (row < M)
      s[row] = e * w[row];
    else
      pref[row - M] = e;
  }
}

__device__ inline unsigned swz_fb(unsigned off) {
  return off ^ (((off >> 8) & 7u) << 4);
}
__device__ inline void split8(float x0, float x1, float x2, float x3,
                              float x4, float x5, float x6, float x7,
                              float scale, short8& hi, short8& lo) {
  float xs[8] = {x0, x1, x2, x3, x4, x5, x6, x7};
#pragma unroll
  for (int i = 0; i < 8; ++i) {
    float v = xs[i] * scale;
    unsigned u = __float_as_uint(v);
    float hf = __uint_as_float(u & 0xffff0000u);
    float rr = v - hf;
    hi[i] = (short)(u >> 16);
    lo[i] = (short)(__float_as_uint(rr) >> 16);
  }
}

__global__ __launch_bounds__(256, 2) void gk_main_fb(
    const float* __restrict__ Xnew, const float* __restrict__ Xtr,
    const float* __restrict__ s, const float* __restrict__ pref,
    float* __restrict__ out, int N, int M, int mchunk) {
  __shared__ __attribute__((aligned(16))) char lds[33024];
  const int t = threadIdx.x;
  const int l = t & 63;
  const int w = t >> 6;
  const int lrow = l & 31;
  const int lk = l >> 5;
  const int n0 = blockIdx.x * 256;
  const int M0 = blockIdx.y * mchunk;
  const int iters = mchunk >> 6;

  short8 bh[2][8], bl[2][8];
  {
    const int colbase = n0 + w * 64;
#pragma unroll
    for (int nf = 0; nf < 2; ++nf) {
      int col = colbase + nf * 32 + lrow;
      const float* p = Xnew + (size_t)col * 128 + lk * 8;
#pragma unroll
      for (int kf = 0; kf < 8; ++kf) {
        float4 f0 = *(const float4*)(p + kf * 16);
        float4 f1 = *(const float4*)(p + kf * 16 + 4);
        split8(f0.x, f0.y, f0.z, f0.w, f1.x, f1.y, f1.z, f1.w, LOG2E,
               bh[nf][kf], bl[nf][kf]);
      }
    }
  }

  float out0 = 0.f, out1 = 0.f;
  float4 ga[4][2];
  float sreg = 0.f;
  {
    const float* abase = Xtr + (size_t)M0 * 128;
#pragma unroll
    for (int j = 0; j < 4; ++j) {
      int c = t + j * 256;
      int row = c >> 4, oct = c & 15;
      const float* p = abase + (size_t)row * 128 + oct * 8;
      ga[j][0] = *(const float4*)p;
      ga[j][1] = *(const float4*)(p + 4);
    }
    if (t < 64) sreg = s[M0 + t];
  }

#pragma unroll 1
  for (int it = 0; it < iters; ++it) {
    __syncthreads();
#pragma unroll
    for (int j = 0; j < 4; ++j) {
      int c = t + j * 256;
      int row = c >> 4, oct = c & 15;
      unsigned off = swz_fb((unsigned)(row * 256 + oct * 16));
      short8 hi, lo;
      split8(ga[j][0].x, ga[j][0].y, ga[j][0].z, ga[j][0].w, ga[j][1].x,
             ga[j][1].y, ga[j][1].z, ga[j][1].w, 1.0f, hi, lo);
      *(short8*)(lds + off) = hi;
      *(short8*)(lds + 16384 + off) = lo;
    }
    if (t < 64) *(float*)(lds + 32768 + t * 4) = sreg;
    __syncthreads();
    if (it + 1 < iters) {
      const float* abase = Xtr + (size_t)(M0 + (it + 1) * 64) * 128;
#pragma unroll
      for (int j = 0; j < 4; ++j) {
        int c = t + j * 256;
        int row = c >> 4, oct = c & 15;
        const float* p = abase + (size_t)row * 128 + oct * 8;
        ga[j][0] = *(const float4*)p;
        ga[j][1] = *(const float4*)(p + 4);
      }
      if (t < 64) sreg = s[M0 + (it + 1) * 64 + t];
    }
#pragma unroll
    for (int mf = 0; mf < 2; ++mf) {
      f32x16 acc0 = {0, 0, 0, 0, 0, 0, 0, 0, 0, 0, 0, 0, 0, 0, 0, 0};
      f32x16 acc1 = {0, 0, 0, 0, 0, 0, 0, 0, 0, 0, 0, 0, 0, 0, 0, 0};
#pragma unroll
      for (int kf = 0; kf < 8; ++kf) {
        unsigned off =
            swz_fb((unsigned)((mf * 32 + lrow) * 256 + kf * 32 + lk * 16));
        short8 ah = *(const short8*)(lds + off);
        short8 al = *(const short8*)(lds + 16384 + off);
        acc0 = __builtin_amdgcn_mfma_f32_32x32x16_bf16(ah, bh[0][kf], acc0, 0, 0, 0);
        acc1 = __builtin_amdgcn_mfma_f32_32x32x16_bf16(ah, bh[1][kf], acc1, 0, 0, 0);
        acc0 = __builtin_amdgcn_mfma_f32_32x32x16_bf16(ah, bl[0][kf], acc0, 0, 0, 0);
        acc1 = __builtin_amdgcn_mfma_f32_32x32x16_bf16(ah, bl[1][kf], acc1, 0, 0, 0);
        acc0 = __builtin_amdgcn_mfma_f32_32x32x16_bf16(al, bh[0][kf], acc0, 0, 0, 0);
        acc1 = __builtin_amdgcn_mfma_f32_32x32x16_bf16(al, bh[1][kf], acc1, 0, 0, 0);
      }
      const float* sl = (const float*)(lds + 32768 + mf * 128);
#pragma unroll
      for (int r = 0; r < 16; ++r) {
        int row = (r & 3) + 8 * (r >> 2) + 4 * lk;
        float sv = sl[row];
        out0 += fast_exp2(acc0[r]) * sv;
        out1 += fast_exp2(acc1[r]) * sv;
      }
    }
  }
  out0 += __shfl_xor(out0, 32, 64);
  out1 += __shfl_xor(out1, 32, 64);
  if (l < 32) {
    int n = n0 + w * 64 + l;
    atomicAdd(out + n, pref[n] * out0);
    n += 32;
    atomicAdd(out + n, pref[n] * out1);
  }
}

extern "C" void kernel_launch(void* const* d_in, const int* in_sizes, int n_in,
                              void* d_out, int out_size, void* d_ws,
                              size_t ws_size, hipStream_t stream) {
  const float* Xnew = (const float*)d_in[0];
  const float* Xtr = (const float*)d_in[1];
  const float* wts = (const float*)d_in[2];
  float* out = (float*)d_out;

  const int N = in_sizes[0] / 128;  // 8192
  const int M = in_sizes[1] / 128;  // 32768

  char* ws = (char*)d_ws;
  float* s_ws = (float*)ws;                 // [M]
  char* planes_ws = ws + (size_t)M * 4;     // [M*256 B], 16B-aligned
  const size_t need = (size_t)M * 4 + (size_t)M * 256;

  hipMemsetAsync(d_out, 0, (size_t)N * sizeof(float), stream);

  if (ws_size >= need) {
    gk_conv_s<<<dim3(M * 8 / 256), 256, 0, stream>>>(Xtr, wts, planes_ws,
                                                     s_ws, M);
    // grid: 64 col-groups x 12 m-splits = 768 blocks = exactly 3 per CU.
    // chunk = 2752 rows (43 pairs of 64); last block 2496 rows (39 pairs).
    const int SPLIT = 12;
    const int CH = ((M + SPLIT - 1) / SPLIT + 63) & ~63;  // 2752
    dim3 grid(N / 128, SPLIT);
    gk_main_i8<<<grid, 256, 49920, stream>>>(Xnew, planes_ws, s_ws, out, N, M,
                                             CH);
  } else {
    float* pref_ws = s_ws + M;
    int rows = M + N;
    gk_prep<<<dim3((rows + 3) / 4), 256, 0, stream>>>(Xnew, Xtr, wts, s_ws,
                                                      pref_ws, M, N);
    const int SPLIT = 16;
    dim3 grid(N / 256, SPLIT);
    gk_main_fb<<<grid, 256, 0, stream>>>(Xnew, Xtr, s_ws, pref_ws, out, N, M,
                                         M / SPLIT);
  }
}

// Round 17
// 122.708 us; speedup vs baseline: 1.0708x; 1.0685x over previous
//
#include <hip/hip_runtime.h>
#include <stdint.h>

typedef __attribute__((ext_vector_type(4))) int i32x4;
typedef __attribute__((ext_vector_type(16))) int i32x16;
typedef __attribute__((ext_vector_type(8))) short short8;
typedef __attribute__((ext_vector_type(16))) float f32x16;

#define LOG2E 1.4426950408889634f
// Power-of-2 quantization scales (A raw, B pre-scaled by log2e):
//   hi = rint(x*16), lo = rint((x - hi/16)*4096)
//   c = (float)((hh << 8) + m) * 2^-16
#define S1 16.0f
#define S1_INV 0.0625f
#define S2 4096.0f
#define K2 (1.0f / 65536.0f)

__device__ inline float fast_exp2(float x) {
#if __has_builtin(__builtin_amdgcn_exp2f)
  return __builtin_amdgcn_exp2f(x);
#else
  float r;
  asm volatile("v_exp_f32 %0, %1" : "=v"(r) : "v"(x));
  return r;
#endif
}

__device__ inline void gload16(const void* g, void* l) {
  __builtin_amdgcn_global_load_lds(
      (const __attribute__((address_space(1))) void*)g,
      (__attribute__((address_space(3))) void*)l, 16, 0, 0);
}
__device__ inline void gload4(const void* g, void* l) {
  __builtin_amdgcn_global_load_lds(
      (const __attribute__((address_space(1))) void*)g,
      (__attribute__((address_space(3))) void*)l, 4, 0, 0);
}

// Quantize 4 floats (optionally pre-scaled) to int8 hi/lo pairs packed into
// one int each (byte j = element j).
__device__ inline void q4(float4 v, float pre, int& hw, int& lw) {
  float xs[4] = {v.x, v.y, v.z, v.w};
  int h = 0, l = 0;
#pragma unroll
  for (int j = 0; j < 4; ++j) {
    float x = xs[j] * pre;
    float hf = rintf(fminf(fmaxf(x * S1, -127.f), 127.f));
    float rf = x - hf * S1_INV;
    float lf = rintf(fminf(fmaxf(rf * S2, -127.f), 127.f));
    h |= ((int)hf & 255) << (8 * j);
    l |= ((int)lf & 255) << (8 * j);
  }
  hw = h;
  lw = l;
}

// ---------------------------------------------------------------------------
// FUSED conversion + s: Xtr f32 -> int8 hi/lo fragment-tiled planes
// ([plane(2)][kf(4)][lk(2)][row(32)][16B] per 32-row 8 KB tile) AND
// s[m] = exp(-||y_m||^2/2) * w[m] via 8-lane in-wave reduction.
// ---------------------------------------------------------------------------
__global__ __launch_bounds__(256) void gk_conv_s(const float* __restrict__ Xtr,
                                                 const float* __restrict__ wts,
                                                 char* __restrict__ planes,
                                                 float* __restrict__ s, int M) {
  int g = blockIdx.x * 256 + threadIdx.x;  // granule id: row*8 + gr
  int row = g >> 3;
  int gr = g & 7;  // 16 k-elems: kf = gr>>1, lk = gr&1
  if (row >= M) return;
  const float* p = Xtr + (size_t)row * 128 + gr * 16;
  int hw[4], lw[4];
  float ss = 0.f;
#pragma unroll
  for (int i = 0; i < 4; ++i) {
    float4 v = *(const float4*)(p + i * 4);
    ss += v.x * v.x + v.y * v.y + v.z * v.z + v.w * v.w;
    q4(v, 1.0f, hw[i], lw[i]);
  }
  // reduce over the 8 lanes of this row (lanes differ in bits 0..2)
  ss += __shfl_xor(ss, 1, 64);
  ss += __shfl_xor(ss, 2, 64);
  ss += __shfl_xor(ss, 4, 64);
  if (gr == 0) s[row] = expf(-0.5f * ss) * wts[row];

  int T = row >> 5, r = row & 31;
  size_t base = (size_t)T * 8192 + (gr >> 1) * 1024 + (gr & 1) * 512 + r * 16;
  *(i32x4*)(planes + base) = (i32x4){hw[0], hw[1], hw[2], hw[3]};
  *(i32x4*)(planes + base + 4096) = (i32x4){lw[0], lw[1], lw[2], lw[3]};
}

// ---------------------------------------------------------------------------
// Main kernel (i8x2, 2-deep accumulator pipeline, counted-vmcnt 4-buffer).
// Block = 512 thr = 8 waves; wave tile = 32 A-rows x 32 B-cols.
// Pipeline per iter t: [sched_barrier; issue stage(t+2) -> buf (t+2)&3;
// 12 MFMA(t) -> accCur; EPILOGUE(accPrev, tile t-1) in the SAME region
// (independent regs -> VALU overlaps MFMA issue; hides the acc/AGPR reads);
// s_waitcnt vmcnt(2) (own stage(t+1) landed; cross-wave via barrier);
// s_barrier]. WAR safe: stage(t+2) writes buf (t-2)&3 (readers done 2
// barriers ago); EPI(t-1) finishes before the barrier that precedes
// stage(t+3)'s issue. Tail uses a clamped dummy stage for uniform counts.
// pref[n] computed IN-REGISTER from the same Xnew loads used for B-quant.
// Grid 32x16 = 512 blocks = 2/CU; LDS 4x8192 + 4x256 = 33792 B.
// This is the session's best-measured configuration (122.17 us, absmax
// 2.02e-28); composed-floor model ~109 us main -> within ~4%.
// ---------------------------------------------------------------------------
__global__ __launch_bounds__(512, 4) void gk_main_i8(
    const float* __restrict__ Xnew, const char* __restrict__ planes,
    const float* __restrict__ s, float* __restrict__ out, int N, int M,
    int mchunk) {
  extern __shared__ char dlds[];  // [4 x 8192 A-bufs][4 x 256 s-bufs]

  const int t = threadIdx.x;
  const int l = t & 63;
  const int w = t >> 6;   // wave 0..7
  const int cl = l & 31;  // B-col within frag / A-row within frag
  const int lk = l >> 5;  // k-chunk half

  const int n0 = blockIdx.x * 256;
  const int M0 = blockIdx.y * mchunk;
  const int iters = mchunk >> 5;  // 64 (even, >= 4)
  const int T0 = M0 >> 5;

#define STAGE(tt)                                                       \
  {                                                                     \
    int st_ = ((tt) < iters) ? (tt) : (iters - 1); /* clamped dummy */  \
    gload16(planes + (size_t)(T0 + st_) * 8192 + t * 16,                \
            dlds + ((tt)&3) * 8192 + t * 16);                           \
    gload4(s + M0 + st_ * 32 + l, dlds + 32768 + ((tt)&3) * 256);       \
  }

#define COMPUTE(acc_hh, acc_m, tile)                                    \
  {                                                                     \
    const char* buf_ = dlds + ((tile)&3) * 8192;                        \
    acc_hh = zero16;                                                    \
    acc_m = zero16;                                                     \
    __builtin_amdgcn_s_setprio(1);                                      \
    _Pragma("unroll") for (int kf = 0; kf < 4; ++kf) {                  \
      const char* kb_ = buf_ + kf * 1024 + lk * 512 + cl * 16;          \
      i32x4 ah_ = *(const i32x4*)(kb_);                                 \
      i32x4 al_ = *(const i32x4*)(kb_ + 4096);                          \
      acc_hh = __builtin_amdgcn_mfma_i32_32x32x32_i8(ah_, bh[kf], acc_hh, 0, 0, 0); \
      acc_m = __builtin_amdgcn_mfma_i32_32x32x32_i8(ah_, bl[kf], acc_m, 0, 0, 0);   \
      acc_m = __builtin_amdgcn_mfma_i32_32x32x32_i8(al_, bh[kf], acc_m, 0, 0, 0);   \
    }                                                                   \
    __builtin_amdgcn_s_setprio(0);                                      \
  }

  // epilogue: c = ((hh<<8)+m)*2^-16 = log2e*<x,y>; exp2; * s[m].
  // C/D layout (verified): col = lane&31, row = (reg&3)+8*(reg>>2)+4*lk
#define EPI(acc_hh, acc_m, tile)                                        \
  {                                                                     \
    const float4* sl4_ =                                                \
        (const float4*)(dlds + 32768 + ((tile)&3) * 256);               \
    _Pragma("unroll") for (int q = 0; q < 4; ++q) {                     \
      float4 sv_ = sl4_[q * 2 + lk];                                    \
      _Pragma("unroll") for (int j = 0; j < 4; ++j) {                   \
        int r_ = q * 4 + j;                                             \
        float c_ = (float)((acc_hh[r_] << 8) + acc_m[r_]) * K2;         \
        out0 += fast_exp2(c_) * (&sv_.x)[j];                            \
      }                                                                 \
    }                                                                   \
  }

  const i32x16 zero16 = {0, 0, 0, 0, 0, 0, 0, 0, 0, 0, 0, 0, 0, 0, 0, 0};

  // ---- issue stage(0), stage(1) first so DMA overlaps B-init --------------
  STAGE(0);
  STAGE(1);

  // ---- per-wave B-panel (32 cols x K=128, i8 hi/lo, log2e folded) and
  // ---- in-register pref for the wave's cols (reuses the same loads) -------
  i32x4 bh[4], bl[4];
  float pref;
  {
    float ss = 0.f;
    const float* pc = Xnew + (size_t)(n0 + w * 32 + cl) * 128;
#pragma unroll
    for (int kf = 0; kf < 4; ++kf) {
      const float* p = pc + kf * 32 + lk * 16;
      int hw[4], lw[4];
#pragma unroll
      for (int i = 0; i < 4; ++i) {
        float4 v = *(const float4*)(p + i * 4);
        ss += v.x * v.x + v.y * v.y + v.z * v.z + v.w * v.w;
        q4(v, LOG2E, hw[i], lw[i]);
      }
      bh[kf] = (i32x4){hw[0], hw[1], hw[2], hw[3]};
      bl[kf] = (i32x4){lw[0], lw[1], lw[2], lw[3]};
    }
    ss += __shfl_xor(ss, 32, 64);  // combine the two k-halves of the col
    pref = expf(-0.5f * ss);
  }

  float out0 = 0.f;
  i32x16 hhA, mA, hhB, mB;

  asm volatile("s_waitcnt vmcnt(2)" ::: "memory");  // own stage(0) landed
  __builtin_amdgcn_s_barrier();                     // all waves' stage(0) in

  // ---- iter 0 (peeled: no previous acc to epilogue) -----------------------
  __builtin_amdgcn_sched_barrier(0);
  STAGE(2);
  COMPUTE(hhA, mA, 0);
  asm volatile("s_waitcnt vmcnt(2)" ::: "memory");
  __builtin_amdgcn_s_barrier();

  // ---- pairs t = (tt, tt+1), tt = 1,3,...,iters-3 -------------------------
#pragma unroll 1
  for (int tt = 1; tt < iters - 1; tt += 2) {
    __builtin_amdgcn_sched_barrier(0);
    STAGE(tt + 2);
    COMPUTE(hhB, mB, tt);
    EPI(hhA, mA, tt - 1);
    asm volatile("s_waitcnt vmcnt(2)" ::: "memory");
    __builtin_amdgcn_s_barrier();

    __builtin_amdgcn_sched_barrier(0);
    STAGE(tt + 3);
    COMPUTE(hhA, mA, tt + 1);
    EPI(hhB, mB, tt);
    asm volatile("s_waitcnt vmcnt(2)" ::: "memory");
    __builtin_amdgcn_s_barrier();
  }

  // ---- tail: tile iters-1, then drain both epilogues ----------------------
  __builtin_amdgcn_sched_barrier(0);
  COMPUTE(hhB, mB, iters - 1);
  EPI(hhA, mA, iters - 2);
  EPI(hhB, mB, iters - 1);

  // ---- reduce row-halves (lane>>5) + atomic -------------------------------
  out0 += __shfl_xor(out0, 32, 64);
  if (l < 32) {
    int n = n0 + w * 32 + l;
    atomicAdd(out + n, pref * out0);
  }
#undef STAGE
#undef COMPUTE
#undef EPI
}

// ---------------------------------------------------------------------------
// FALLBACK (ws too small): bf16x3 R1-structure (known-good ~185 us) + prep.
// ---------------------------------------------------------------------------
__global__ __launch_bounds__(256) void gk_prep(
    const float* __restrict__ Xnew, const float* __restrict__ Xtr,
    const float* __restrict__ w, float* __restrict__ s,
    float* __restrict__ pref, int M, int N) {
  int row = blockIdx.x * 4 + (threadIdx.x >> 6);
  int lane = threadIdx.x & 63;
  if (row >= M + N) return;
  const float* src =
      (row < M) ? (Xtr + (size_t)row * 128) : (Xnew + (size_t)(row - M) * 128);
  float2 v = *(const float2*)(src + lane * 2);
  float ss = v.x * v.x + v.y * v.y;
#pragma unroll
  for (int o = 32; o >= 1; o >>= 1) ss += __shfl_xor(ss, o, 64);
  if (lane == 0) {
    float e = expf(-0.5f * ss);
    if (row < M)
      s[row] = e * w[row];
    else
      pref[row - M] = e;
  }
}

__device__ inline unsigned swz_fb(unsigned off) {
  return off ^ (((off >> 8) & 7u) << 4);
}
__device__ inline void split8(float x0, float x1, float x2, float x3,
                              float x4, float x5, float x6, float x7,
                              float scale, short8& hi, short8& lo) {
  float xs[8] = {x0, x1, x2, x3, x4, x5, x6, x7};
#pragma unroll
  for (int i = 0; i < 8; ++i) {
    float v = xs[i] * scale;
    unsigned u = __float_as_uint(v);
    float hf = __uint_as_float(u & 0xffff0000u);
    float rr = v - hf;
    hi[i] = (short)(u >> 16);
    lo[i] = (short)(__float_as_uint(rr) >> 16);
  }
}

__global__ __launch_bounds__(256, 2) void gk_main_fb(
    const float* __restrict__ Xnew, const float* __restrict__ Xtr,
    const float* __restrict__ s, const float* __restrict__ pref,
    float* __restrict__ out, int N, int M, int mchunk) {
  __shared__ __attribute__((aligned(16))) char lds[33024];
  const int t = threadIdx.x;
  const int l = t & 63;
  const int w = t >> 6;
  const int lrow = l & 31;
  const int lk = l >> 5;
  const int n0 = blockIdx.x * 256;
  const int M0 = blockIdx.y * mchunk;
  const int iters = mchunk >> 6;

  short8 bh[2][8], bl[2][8];
  {
    const int colbase = n0 + w * 64;
#pragma unroll
    for (int nf = 0; nf < 2; ++nf) {
      int col = colbase + nf * 32 + lrow;
      const float* p = Xnew + (size_t)col * 128 + lk * 8;
#pragma unroll
      for (int kf = 0; kf < 8; ++kf) {
        float4 f0 = *(const float4*)(p + kf * 16);
        float4 f1 = *(const float4*)(p + kf * 16 + 4);
        split8(f0.x, f0.y, f0.z, f0.w, f1.x, f1.y, f1.z, f1.w, LOG2E,
               bh[nf][kf], bl[nf][kf]);
      }
    }
  }

  float out0 = 0.f, out1 = 0.f;
  float4 ga[4][2];
  float sreg = 0.f;
  {
    const float* abase = Xtr + (size_t)M0 * 128;
#pragma unroll
    for (int j = 0; j < 4; ++j) {
      int c = t + j * 256;
      int row = c >> 4, oct = c & 15;
      const float* p = abase + (size_t)row * 128 + oct * 8;
      ga[j][0] = *(const float4*)p;
      ga[j][1] = *(const float4*)(p + 4);
    }
    if (t < 64) sreg = s[M0 + t];
  }

#pragma unroll 1
  for (int it = 0; it < iters; ++it) {
    __syncthreads();
#pragma unroll
    for (int j = 0; j < 4; ++j) {
      int c = t + j * 256;
      int row = c >> 4, oct = c & 15;
      unsigned off = swz_fb((unsigned)(row * 256 + oct * 16));
      short8 hi, lo;
      split8(ga[j][0].x, ga[j][0].y, ga[j][0].z, ga[j][0].w, ga[j][1].x,
             ga[j][1].y, ga[j][1].z, ga[j][1].w, 1.0f, hi, lo);
      *(short8*)(lds + off) = hi;
      *(short8*)(lds + 16384 + off) = lo;
    }
    if (t < 64) *(float*)(lds + 32768 + t * 4) = sreg;
    __syncthreads();
    if (it + 1 < iters) {
      const float* abase = Xtr + (size_t)(M0 + (it + 1) * 64) * 128;
#pragma unroll
      for (int j = 0; j < 4; ++j) {
        int c = t + j * 256;
        int row = c >> 4, oct = c & 15;
        const float* p = abase + (size_t)row * 128 + oct * 8;
        ga[j][0] = *(const float4*)p;
        ga[j][1] = *(const float4*)(p + 4);
      }
      if (t < 64) sreg = s[M0 + (it + 1) * 64 + t];
    }
#pragma unroll
    for (int mf = 0; mf < 2; ++mf) {
      f32x16 acc0 = {0, 0, 0, 0, 0, 0, 0, 0, 0, 0, 0, 0, 0, 0, 0, 0};
      f32x16 acc1 = {0, 0, 0, 0, 0, 0, 0, 0, 0, 0, 0, 0, 0, 0, 0, 0};
#pragma unroll
      for (int kf = 0; kf < 8; ++kf) {
        unsigned off =
            swz_fb((unsigned)((mf * 32 + lrow) * 256 + kf * 32 + lk * 16));
        short8 ah = *(const short8*)(lds + off);
        short8 al = *(const short8*)(lds + 16384 + off);
        acc0 = __builtin_amdgcn_mfma_f32_32x32x16_bf16(ah, bh[0][kf], acc0, 0, 0, 0);
        acc1 = __builtin_amdgcn_mfma_f32_32x32x16_bf16(ah, bh[1][kf], acc1, 0, 0, 0);
        acc0 = __builtin_amdgcn_mfma_f32_32x32x16_bf16(ah, bl[0][kf], acc0, 0, 0, 0);
        acc1 = __builtin_amdgcn_mfma_f32_32x32x16_bf16(ah, bl[1][kf], acc1, 0, 0, 0);
        acc0 = __builtin_amdgcn_mfma_f32_32x32x16_bf16(al, bh[0][kf], acc0, 0, 0, 0);
        acc1 = __builtin_amdgcn_mfma_f32_32x32x16_bf16(al, bh[1][kf], acc1, 0, 0, 0);
      }
      const float* sl = (const float*)(lds + 32768 + mf * 128);
#pragma unroll
      for (int r = 0; r < 16; ++r) {
        int row = (r & 3) + 8 * (r >> 2) + 4 * lk;
        float sv = sl[row];
        out0 += fast_exp2(acc0[r]) * sv;
        out1 += fast_exp2(acc1[r]) * sv;
      }
    }
  }
  out0 += __shfl_xor(out0, 32, 64);
  out1 += __shfl_xor(out1, 32, 64);
  if (l < 32) {
    int n = n0 + w * 64 + l;
    atomicAdd(out + n, pref[n] * out0);
    n += 32;
    atomicAdd(out + n, pref[n] * out1);
  }
}

extern "C" void kernel_launch(void* const* d_in, const int* in_sizes, int n_in,
                              void* d_out, int out_size, void* d_ws,
                              size_t ws_size, hipStream_t stream) {
  const float* Xnew = (const float*)d_in[0];
  const float* Xtr = (const float*)d_in[1];
  const float* wts = (const float*)d_in[2];
  float* out = (float*)d_out;

  const int N = in_sizes[0] / 128;  // 8192
  const int M = in_sizes[1] / 128;  // 32768

  char* ws = (char*)d_ws;
  float* s_ws = (float*)ws;                 // [M]
  char* planes_ws = ws + (size_t)M * 4;     // [M*256 B], 16B-aligned
  const size_t need = (size_t)M * 4 + (size_t)M * 256;

  hipMemsetAsync(d_out, 0, (size_t)N * sizeof(float), stream);

  if (ws_size >= need) {
    gk_conv_s<<<dim3(M * 8 / 256), 256, 0, stream>>>(Xtr, wts, planes_ws,
                                                     s_ws, M);
    const int SPLIT = 16;  // 32 x 16 = 512 blocks = exactly 2 per CU
    dim3 grid(N / 256, SPLIT);
    gk_main_i8<<<grid, 512, 33792, stream>>>(Xnew, planes_ws, s_ws, out, N, M,
                                             M / SPLIT);
  } else {
    // fallback needs s + pref arrays
    float* pref_ws = s_ws + M;
    int rows = M + N;
    gk_prep<<<dim3((rows + 3) / 4), 256, 0, stream>>>(Xnew, Xtr, wts, s_ws,
                                                      pref_ws, M, N);
    const int SPLIT = 16;
    dim3 grid(N / 256, SPLIT);
    gk_main_fb<<<grid, 256, 0, stream>>>(Xnew, Xtr, s_ws, pref_ws, out, N, M,
                                         M / SPLIT);
  }
}